// Round 10
// baseline (278.448 us; speedup 1.0000x reference)
//
#include <hip/hip_runtime.h>
#include <math.h>

// Problem: S=4096, D=512, H=8, KVH=4, DH=64, M=64, K=8 (B=1)
// ARITHMETIC CONTRACT (frozen, round 5 green): selection-critical path
// emulates numpy-f32 op-for-op:
//  - QKV gemm: per output, sequential f32 fmaf chain in k-ascending order,
//    KC=384 panel split, final __fadd_rn(acc1, acc2)
//  - k1/k2 sums: sequential f32 adds in axis order
//  - stage-1 scores: sequential fmaf chain over d (0..31)   [in GEMM]
//  - stage-2 einsum: sequential f32 mul+add (NOT fma) over d (0..63)
//  - tables: correctly-rounded f32 (f64 then round)
//  - top-k: descending, ties -> lower index
//  - softmax: *0.125, __expf (value-path), pairwise-8 sum, f32 div
// Round 9: 128x128 tile / 8x8-per-thread GEMM (same chain order, bit-identical);
// next-tile global loads issued before compute (latency overlap).

// Workspace (floats)
static constexpr size_t OFF_QKV = 0;              // 4096*1024 (reused as scores)
static constexpr size_t OFF_Q   = 4194304;        // 8*4096*64   q[h][s][d]
static constexpr size_t OFF_K   = 6291456;        // 4*4096*64   k[kvh][s][d]
static constexpr size_t OFF_V   = 7340032;        // 4*4096*64   v[kvh][s][d]
static constexpr size_t OFF_COS = 8388608;        // 4096*32
static constexpr size_t OFF_SIN = 8519680;        // 4096*32
static constexpr size_t OFF_K1  = 8650752;        // 4*64*32     k1[kvh][r][d]
static constexpr size_t OFF_K2  = 8658944;        // 4*64*32     k2[kvh][c][d]
static constexpr size_t OFF_O   = 8667136;        // 4096*512
static constexpr size_t OFF_W   = 10764288;       // 1024*512

#define LDB 132   // 128-tile GEMM LDS leading-dim pad

__device__ __forceinline__ float rdlane_f(float v, int lane) {
  return __int_as_float(__builtin_amdgcn_readlane(__float_as_int(v), lane));
}

__global__ __launch_bounds__(256) void freq_table_kernel(float* __restrict__ cosT,
    float* __restrict__ sinT) {
  int idx = blockIdx.x * 256 + threadIdx.x;   // 0..131071
  int s = idx >> 5;
  int dp = idx & 31;
  double e = (double)dp * (1.0 / 32.0);
  float pf = (float)pow(10000.0, e);
  float invf = 1.0f / pf;
  float argf = __fmul_rn((float)s, invf);
  cosT[idx] = (float)cos((double)argf);
  sinT[idx] = (float)sin((double)argf);
}

// 128x128-tile NT gemm, 8x8 outputs/thread, chain-order-preserving, KC split.
// C[M][N] = A[M][512] * B[N][512]^T; per-output fmaf chain in k-ascending
// order, acc1 for k<SPLIT, acc2 for k>=SPLIT, C = fl32(acc1+acc2).
template <int SPLIT>
__global__ __launch_bounds__(256) void gemm128_chain(const float* __restrict__ A,
    const float* __restrict__ B, float* __restrict__ C, int N) {
  __shared__ float As[16 * LDB];
  __shared__ float Bs[16 * LDB];
  const int tid = threadIdx.x;
  const int bm = blockIdx.y, bn = blockIdx.x;
  const int lrow = tid >> 1;          // 0..127
  const int lko = (tid & 1) << 3;     // 0 or 8
  const int ty = tid >> 4;            // 0..15 -> rows ty*8..+7
  const int tx = tid & 15;            // 0..15 -> cols tx*8..+7
  const float* Ap = A + (size_t)(bm * 128 + lrow) * 512 + lko;
  const float* Bp = B + (size_t)(bn * 128 + lrow) * 512 + lko;
  float acc1[8][8] = {{0.f}};
  float acc2[8][8] = {{0.f}};
  float4 a0 = *(const float4*)(Ap + 0);
  float4 a1 = *(const float4*)(Ap + 4);
  float4 b0 = *(const float4*)(Bp + 0);
  float4 b1 = *(const float4*)(Bp + 4);
  for (int kt = 0; kt < 512; kt += 16) {
    __syncthreads();   // previous tile's compute done
    As[(lko + 0) * LDB + lrow] = a0.x;
    As[(lko + 1) * LDB + lrow] = a0.y;
    As[(lko + 2) * LDB + lrow] = a0.z;
    As[(lko + 3) * LDB + lrow] = a0.w;
    As[(lko + 4) * LDB + lrow] = a1.x;
    As[(lko + 5) * LDB + lrow] = a1.y;
    As[(lko + 6) * LDB + lrow] = a1.z;
    As[(lko + 7) * LDB + lrow] = a1.w;
    Bs[(lko + 0) * LDB + lrow] = b0.x;
    Bs[(lko + 1) * LDB + lrow] = b0.y;
    Bs[(lko + 2) * LDB + lrow] = b0.z;
    Bs[(lko + 3) * LDB + lrow] = b0.w;
    Bs[(lko + 4) * LDB + lrow] = b1.x;
    Bs[(lko + 5) * LDB + lrow] = b1.y;
    Bs[(lko + 6) * LDB + lrow] = b1.z;
    Bs[(lko + 7) * LDB + lrow] = b1.w;
    __syncthreads();
    if (kt + 16 < 512) {               // issue next-tile loads before compute
      a0 = *(const float4*)(Ap + kt + 16);
      a1 = *(const float4*)(Ap + kt + 20);
      b0 = *(const float4*)(Bp + kt + 16);
      b1 = *(const float4*)(Bp + kt + 20);
    }
    if (SPLIT != 0 && kt >= SPLIT) {
      #pragma unroll
      for (int k = 0; k < 16; ++k) {
        float4 al = *(const float4*)(&As[k * LDB + (ty << 3)]);
        float4 ah = *(const float4*)(&As[k * LDB + (ty << 3) + 4]);
        float4 bl = *(const float4*)(&Bs[k * LDB + (tx << 3)]);
        float4 bh = *(const float4*)(&Bs[k * LDB + (tx << 3) + 4]);
        float af[8] = {al.x, al.y, al.z, al.w, ah.x, ah.y, ah.z, ah.w};
        float bf[8] = {bl.x, bl.y, bl.z, bl.w, bh.x, bh.y, bh.z, bh.w};
        #pragma unroll
        for (int i2 = 0; i2 < 8; ++i2)
          #pragma unroll
          for (int j2 = 0; j2 < 8; ++j2)
            acc2[i2][j2] = fmaf(af[i2], bf[j2], acc2[i2][j2]);
      }
    } else {
      #pragma unroll
      for (int k = 0; k < 16; ++k) {
        float4 al = *(const float4*)(&As[k * LDB + (ty << 3)]);
        float4 ah = *(const float4*)(&As[k * LDB + (ty << 3) + 4]);
        float4 bl = *(const float4*)(&Bs[k * LDB + (tx << 3)]);
        float4 bh = *(const float4*)(&Bs[k * LDB + (tx << 3) + 4]);
        float af[8] = {al.x, al.y, al.z, al.w, ah.x, ah.y, ah.z, ah.w};
        float bf[8] = {bl.x, bl.y, bl.z, bl.w, bh.x, bh.y, bh.z, bh.w};
        #pragma unroll
        for (int i2 = 0; i2 < 8; ++i2)
          #pragma unroll
          for (int j2 = 0; j2 < 8; ++j2)
            acc1[i2][j2] = fmaf(af[i2], bf[j2], acc1[i2][j2]);
      }
    }
  }
  #pragma unroll
  for (int i2 = 0; i2 < 8; ++i2) {
    float* Cp = C + (size_t)(bm * 128 + (ty << 3) + i2) * N + bn * 128 + (tx << 3);
    float4 lo, hi;
    if (SPLIT != 0) {
      lo.x = __fadd_rn(acc1[i2][0], acc2[i2][0]);
      lo.y = __fadd_rn(acc1[i2][1], acc2[i2][1]);
      lo.z = __fadd_rn(acc1[i2][2], acc2[i2][2]);
      lo.w = __fadd_rn(acc1[i2][3], acc2[i2][3]);
      hi.x = __fadd_rn(acc1[i2][4], acc2[i2][4]);
      hi.y = __fadd_rn(acc1[i2][5], acc2[i2][5]);
      hi.z = __fadd_rn(acc1[i2][6], acc2[i2][6]);
      hi.w = __fadd_rn(acc1[i2][7], acc2[i2][7]);
    } else {
      lo = make_float4(acc1[i2][0], acc1[i2][1], acc1[i2][2], acc1[i2][3]);
      hi = make_float4(acc1[i2][4], acc1[i2][5], acc1[i2][6], acc1[i2][7]);
    }
    *(float4*)(Cp)     = lo;
    *(float4*)(Cp + 4) = hi;
  }
}

__global__ __launch_bounds__(256) void rope_reshape_kernel(const float* __restrict__ raw,
    const float* __restrict__ cosT, const float* __restrict__ sinT,
    float* __restrict__ qb, float* __restrict__ kb, float* __restrict__ vb) {
  int idx = blockIdx.x * 256 + threadIdx.x;
  int s = idx >> 10;
  int n = idx & 1023;
  float val = raw[idx];
  int d = n & 63;
  if (n < 768) {
    int dp = d & 31;
    float cs = cosT[(s << 5) + dp];
    float sn = sinT[(s << 5) + dp];
    int npart = (n - d) + ((d < 32) ? d + 32 : d - 32);
    float partner = raw[(s << 10) + npart];
    float rot = (d < 32) ? -partner : partner;
    float out = __fadd_rn(__fmul_rn(val, cs), __fmul_rn(rot, sn));
    if (n < 512) {
      int h = n >> 6;
      qb[((size_t)(h * 4096 + s) << 6) + d] = out;
    } else {
      int kvh = (n - 512) >> 6;
      kb[((size_t)(kvh * 4096 + s) << 6) + d] = out;
    }
  } else {
    int kvh = (n - 768) >> 6;
    vb[((size_t)(kvh * 4096 + s) << 6) + d] = val;
  }
}

__global__ __launch_bounds__(256) void k12_np_kernel(const float* __restrict__ kb,
    float* __restrict__ k1t, float* __restrict__ k2t) {
  int id = blockIdx.x * 256 + threadIdx.x;    // 0..16383
  int which = id >> 13;
  int rem = id & 8191;
  int kvh = rem >> 11;
  int rem2 = rem & 2047;
  int i = rem2 >> 5;
  int d = rem2 & 31;
  const float* base = kb + ((size_t)(kvh * 4096) << 6);
  if (which == 0) {
    float acc = base[((size_t)(i * 64) << 6) + d];
    for (int c = 1; c < 64; ++c)
      acc = __fadd_rn(acc, base[((size_t)(i * 64 + c) << 6) + d]);
    k1t[(kvh * 64 + i) * 32 + d] = acc;
  } else {
    float acc = base[((size_t)i << 6) + d + 32];
    for (int r = 1; r < 64; ++r)
      acc = __fadd_rn(acc, base[((size_t)(r * 64 + i) << 6) + d + 32]);
    k2t[(kvh * 64 + i) * 32 + d] = acc;
  }
}

// Stage-1 scores as a tiled GEMM (fmaf chain over d ascending, per output).
// sc[h][s][r]      = chain_d q[h][s][d]    * k1[kvh][r][d]   (r 0..63)
// sc[h][s][64+r]   = chain_d q[h][s][32+d] * k2[kvh][r][d]
__global__ __launch_bounds__(256) void stage1_scores_kernel(
    const float* __restrict__ qb, const float* __restrict__ k1t,
    const float* __restrict__ k2t, float* __restrict__ sc) {
  __shared__ float qs[64 * 68];     // [d][s]
  __shared__ float kd[32 * 132];    // [d][r2]
  const int t = threadIdx.x;
  const int h = blockIdx.y;
  const int s0 = blockIdx.x * 64;
  const int kvh = h >> 1;
  #pragma unroll
  for (int i = 0; i < 16; ++i) {
    int j = t + i * 256;
    int ss = j >> 6, d = j & 63;
    qs[d * 68 + ss] = qb[((size_t)(h * 4096 + s0 + ss) << 6) + d];
  }
  #pragma unroll
  for (int i = 0; i < 8; ++i) {
    int j = t + i * 256;
    int r = j >> 5, d = j & 31;
    kd[d * 132 + r]      = k1t[(kvh * 64 + r) * 32 + d];
    kd[d * 132 + 64 + r] = k2t[(kvh * 64 + r) * 32 + d];
  }
  __syncthreads();
  const int ty = t >> 4;
  const int tx = t & 15;
  const int qrow = (tx >= 8) ? 32 : 0;
  float acc[4][8] = {{0.f}};
  #pragma unroll
  for (int d = 0; d < 32; ++d) {
    float4 a4 = *(const float4*)&qs[(qrow + d) * 68 + (ty << 2)];
    float4 b0 = *(const float4*)&kd[d * 132 + (tx << 3)];
    float4 b1 = *(const float4*)&kd[d * 132 + (tx << 3) + 4];
    float af[4] = {a4.x, a4.y, a4.z, a4.w};
    float bf[8] = {b0.x, b0.y, b0.z, b0.w, b1.x, b1.y, b1.z, b1.w};
    #pragma unroll
    for (int i2 = 0; i2 < 4; ++i2)
      #pragma unroll
      for (int j2 = 0; j2 < 8; ++j2)
        acc[i2][j2] = fmaf(af[i2], bf[j2], acc[i2][j2]);
  }
  #pragma unroll
  for (int i2 = 0; i2 < 4; ++i2) {
    float* p = sc + (((size_t)(h * 4096 + s0 + (ty << 2) + i2)) << 7) + (tx << 3);
    *(float4*)(p)     = make_float4(acc[i2][0], acc[i2][1], acc[i2][2], acc[i2][3]);
    *(float4*)(p + 4) = make_float4(acc[i2][4], acc[i2][5], acc[i2][6], acc[i2][7]);
  }
}

// Values-only bitonic sort (descending).
__device__ __forceinline__ void bitonic64_val_desc(float& v, int lane) {
  #pragma unroll
  for (int k = 2; k <= 64; k <<= 1) {
    #pragma unroll
    for (int j = k >> 1; j >= 1; j >>= 1) {
      float ov = __shfl_xor(v, j, 64);
      bool up = ((lane & k) == 0) == ((lane & j) == 0);
      float mx = fmaxf(v, ov), mn = fminf(v, ov);
      v = up ? mx : mn;
    }
  }
}

// Selection kernel: one wave per (h,s); no LDS data at all.
__global__ __launch_bounds__(256) void attn_sel_kernel(const float* __restrict__ sc,
    const float* __restrict__ qb, const float* __restrict__ vb,
    const float* __restrict__ k1t, const float* __restrict__ k2t,
    float* __restrict__ ob) {
  const int lane = threadIdx.x & 63;
  const int w = blockIdx.x * 4 + (threadIdx.x >> 6);   // w = h*4096 + s
  const int h = w >> 12;
  const int s = w & 4095;
  const int kvh = h >> 1;
  const float* scp = sc + ((size_t)w << 7);
  const float s1 = scp[lane];
  const float s2 = scp[64 + lane];
  const float qv = qb[((size_t)w << 6) + lane];

  float v1 = s1;
  bitonic64_val_desc(v1, lane);
  unsigned long long pack1 = 0, used = 0;
  #pragma unroll
  for (int t = 0; t < 8; ++t) {
    float tv = rdlane_f(v1, t);
    unsigned long long m = __ballot(s1 == tv) & ~used;
    int ix = __ffsll((long long)m) - 1;
    used |= 1ull << ix;
    pack1 |= (unsigned long long)ix << (6 * t);
  }
  float v2 = s2;
  bitonic64_val_desc(v2, lane);
  unsigned long long pack2 = 0;
  used = 0;
  #pragma unroll
  for (int t = 0; t < 8; ++t) {
    float tv = rdlane_f(v2, t);
    unsigned long long m = __ballot(s2 == tv) & ~used;
    int ix = __ffsll((long long)m) - 1;
    used |= 1ull << ix;
    pack2 |= (unsigned long long)ix << (6 * t);
  }

  // stage-2: lane c = it1*8+it2; mul+add chain over d=0..63 (non-fma)
  int r1 = (int)((pack1 >> (6 * (lane >> 3))) & 63);
  int r2 = (int)((pack2 >> (6 * (lane & 7))) & 63);
  const float* k1p = k1t + (size_t)(kvh * 64 + r1) * 32;
  const float* k2p = k2t + (size_t)(kvh * 64 + r2) * 32;
  float c = 0.f;
  #pragma unroll
  for (int dq = 0; dq < 32; dq += 4) {
    float4 kk = *(const float4*)(k1p + dq);
    c = __fadd_rn(c, __fmul_rn(rdlane_f(qv, dq + 0), kk.x));
    c = __fadd_rn(c, __fmul_rn(rdlane_f(qv, dq + 1), kk.y));
    c = __fadd_rn(c, __fmul_rn(rdlane_f(qv, dq + 2), kk.z));
    c = __fadd_rn(c, __fmul_rn(rdlane_f(qv, dq + 3), kk.w));
  }
  #pragma unroll
  for (int dq = 0; dq < 32; dq += 4) {
    float4 kk = *(const float4*)(k2p + dq);
    c = __fadd_rn(c, __fmul_rn(rdlane_f(qv, 32 + dq + 0), kk.x));
    c = __fadd_rn(c, __fmul_rn(rdlane_f(qv, 32 + dq + 1), kk.y));
    c = __fadd_rn(c, __fmul_rn(rdlane_f(qv, 32 + dq + 2), kk.z));
    c = __fadd_rn(c, __fmul_rn(rdlane_f(qv, 32 + dq + 3), kk.w));
  }
  const float scand = c;
  float v3 = c;
  bitonic64_val_desc(v3, lane);
  float cvs[8]; int ccs[8];
  used = 0;
  #pragma unroll
  for (int t = 0; t < 8; ++t) {
    float tv = rdlane_f(v3, t);
    unsigned long long m = __ballot(scand == tv) & ~used;
    int ix = __ffsll((long long)m) - 1;
    used |= 1ull << ix;
    cvs[t] = tv;
    ccs[t] = ix;
  }
  float y[8];
  #pragma unroll
  for (int t = 0; t < 8; ++t) y[t] = cvs[t] * 0.125f;
  float mx = y[0];
  #pragma unroll
  for (int t = 1; t < 8; ++t) if (y[t] > mx) mx = y[t];
  float e[8];
  #pragma unroll
  for (int t = 0; t < 8; ++t) e[t] = __expf(__fsub_rn(y[t], mx));
  float wsum = __fadd_rn(__fadd_rn(__fadd_rn(e[0], e[1]), __fadd_rn(e[2], e[3])),
                         __fadd_rn(__fadd_rn(e[4], e[5]), __fadd_rn(e[6], e[7])));
  const float* vbh = vb + ((size_t)kvh << 18);
  float o = 0.f;
  #pragma unroll
  for (int t = 0; t < 8; ++t) {
    float att = __fdiv_rn(e[t], wsum);
    int row = (int)((pack1 >> (6 * (ccs[t] >> 3))) & 63);
    int col = (int)((pack2 >> (6 * (ccs[t] & 7))) & 63);
    o = __fadd_rn(o, __fmul_rn(att, vbh[((size_t)(row * 64 + col) << 6) + lane]));
  }
  ob[(size_t)s * 512 + (h << 6) + lane] = o;
}

extern "C" void kernel_launch(void* const* d_in, const int* in_sizes, int n_in,
                              void* d_out, int out_size, void* d_ws, size_t ws_size,
                              hipStream_t stream) {
  const float* x  = (const float*)d_in[0];
  const float* Wq = (const float*)d_in[1];
  const float* Wk = (const float*)d_in[2];
  const float* Wv = (const float*)d_in[3];
  const float* Wo = (const float*)d_in[4];
  float* ws = (float*)d_ws;
  float* qkv  = ws + OFF_QKV;
  float* qb   = ws + OFF_Q;
  float* kb   = ws + OFF_K;
  float* vb   = ws + OFF_V;
  float* cosT = ws + OFF_COS;
  float* sinT = ws + OFF_SIN;
  float* k1t  = ws + OFF_K1;
  float* k2t  = ws + OFF_K2;
  float* ob   = ws + OFF_O;
  float* wcat = ws + OFF_W;
  float* scb  = ws + OFF_QKV;   // scores reuse the dead qkv buffer

  hipMemcpyAsync(wcat,             Wq, (size_t)512 * 512 * sizeof(float), hipMemcpyDeviceToDevice, stream);
  hipMemcpyAsync(wcat + 512 * 512, Wk, (size_t)256 * 512 * sizeof(float), hipMemcpyDeviceToDevice, stream);
  hipMemcpyAsync(wcat + 768 * 512, Wv, (size_t)256 * 512 * sizeof(float), hipMemcpyDeviceToDevice, stream);

  freq_table_kernel<<<512, 256, 0, stream>>>(cosT, sinT);
  gemm128_chain<384><<<dim3(1024 / 128, 4096 / 128), 256, 0, stream>>>(x, wcat, qkv, 1024);
  rope_reshape_kernel<<<16384, 256, 0, stream>>>(qkv, cosT, sinT, qb, kb, vb);
  k12_np_kernel<<<64, 256, 0, stream>>>(kb, k1t, k2t);
  stage1_scores_kernel<<<dim3(64, 8), 256, 0, stream>>>(qb, k1t, k2t, scb);
  attn_sel_kernel<<<8192, 256, 0, stream>>>(scb, qb, vb, k1t, k2t, ob);
  gemm128_chain<0><<<dim3(512 / 128, 4096 / 128), 256, 0, stream>>>(ob, Wo, (float*)d_out, 512);
}

// Round 11
// 244.701 us; speedup vs baseline: 1.1379x; 1.1379x over previous
//
#include <hip/hip_runtime.h>
#include <math.h>

// Problem: S=4096, D=512, H=8, KVH=4, DH=64, M=64, K=8 (B=1)
// ARITHMETIC CONTRACT (frozen, round 5 green): selection-critical path
// emulates numpy-f32 op-for-op:
//  - QKV gemm: per output, sequential f32 fmaf chain in k-ascending order,
//    KC=384 panel split, final __fadd_rn(acc1, acc2)   [add now in rope]
//  - k1/k2 sums: sequential f32 adds in axis order
//  - stage-1 scores: sequential fmaf chain over d (0..31)   [in GEMM]
//  - stage-2 einsum: sequential f32 mul+add (NOT fma) over d (0..63)
//  - tables: correctly-rounded f32 (f64 then round)
//  - top-k: descending, ties -> lower index
//  - softmax: *0.125, __expf (value-path), pairwise-8 sum, f32 div
// Round 10: panel-split (grid-z) 128x128 GEMM, single 64-reg accumulator,
// 2-way-conflict LDS mapping (rows/cols {g*4, 64+g*4}); out-gemm split-k
// + combine (value-path).

// Workspace (floats)
static constexpr size_t OFF_P1  = 0;              // 4096*1024 panel1 / scores
static constexpr size_t OFF_P2  = 4194304;        // 4096*1024 panel2 / out partials
static constexpr size_t OFF_Q   = 8388608;        // 8*4096*64   q[h][s][d]
static constexpr size_t OFF_K   = 10485760;       // 4*4096*64   k[kvh][s][d]
static constexpr size_t OFF_V   = 11534336;       // 4*4096*64   v[kvh][s][d]
static constexpr size_t OFF_COS = 12582912;       // 4096*32
static constexpr size_t OFF_SIN = 12713984;       // 4096*32
static constexpr size_t OFF_K1  = 12845056;       // 4*64*32     k1[kvh][r][d]
static constexpr size_t OFF_K2  = 12853248;       // 4*64*32     k2[kvh][c][d]
static constexpr size_t OFF_O   = 12861440;       // 4096*512
static constexpr size_t OFF_W   = 14958592;       // 1024*512

#define LDB 132   // 128-tile GEMM LDS leading-dim pad

__device__ __forceinline__ float rdlane_f(float v, int lane) {
  return __int_as_float(__builtin_amdgcn_readlane(__float_as_int(v), lane));
}

__global__ __launch_bounds__(256) void freq_table_kernel(float* __restrict__ cosT,
    float* __restrict__ sinT) {
  int idx = blockIdx.x * 256 + threadIdx.x;   // 0..131071
  int s = idx >> 5;
  int dp = idx & 31;
  double e = (double)dp * (1.0 / 32.0);
  float pf = (float)pow(10000.0, e);
  float invf = 1.0f / pf;
  float argf = __fmul_rn((float)s, invf);
  cosT[idx] = (float)cos((double)argf);
  sinT[idx] = (float)sin((double)argf);
}

// Panel NT gemm: 128x128 tile, 8x8/thread, single fmaf chain over
// k in [z?ksplit:0, z?512:ksplit), k-ascending. C_z gets the partial sum.
// Thread (ty,tx) owns rows {ty*4+i, 64+ty*4+i}, cols {tx*4+j, 64+tx*4+j}
// -> all LDS b128 reads are 2-way bank aliased (free).
__global__ __launch_bounds__(256) void gemm128_panel(const float* __restrict__ A,
    const float* __restrict__ B, float* __restrict__ C1, float* __restrict__ C2,
    int N, int ksplit) {
  __shared__ float As[16 * LDB];
  __shared__ float Bs[16 * LDB];
  const int tid = threadIdx.x;
  const int z = blockIdx.z;
  const int k0 = z ? ksplit : 0;
  const int k1 = z ? 512 : ksplit;
  float* __restrict__ C = z ? C2 : C1;
  const int bm = blockIdx.y, bn = blockIdx.x;
  const int lrow = tid >> 1;          // 0..127
  const int lko = (tid & 1) << 3;     // 0 or 8
  const int ty = tid >> 4;            // 0..15
  const int tx = tid & 15;            // 0..15
  const float* Ap = A + (size_t)(bm * 128 + lrow) * 512 + lko;
  const float* Bp = B + (size_t)(bn * 128 + lrow) * 512 + lko;
  float acc[8][8] = {{0.f}};
  float4 a0 = *(const float4*)(Ap + k0);
  float4 a1 = *(const float4*)(Ap + k0 + 4);
  float4 b0 = *(const float4*)(Bp + k0);
  float4 b1 = *(const float4*)(Bp + k0 + 4);
  for (int kt = k0; kt < k1; kt += 16) {
    __syncthreads();
    As[(lko + 0) * LDB + lrow] = a0.x;
    As[(lko + 1) * LDB + lrow] = a0.y;
    As[(lko + 2) * LDB + lrow] = a0.z;
    As[(lko + 3) * LDB + lrow] = a0.w;
    As[(lko + 4) * LDB + lrow] = a1.x;
    As[(lko + 5) * LDB + lrow] = a1.y;
    As[(lko + 6) * LDB + lrow] = a1.z;
    As[(lko + 7) * LDB + lrow] = a1.w;
    Bs[(lko + 0) * LDB + lrow] = b0.x;
    Bs[(lko + 1) * LDB + lrow] = b0.y;
    Bs[(lko + 2) * LDB + lrow] = b0.z;
    Bs[(lko + 3) * LDB + lrow] = b0.w;
    Bs[(lko + 4) * LDB + lrow] = b1.x;
    Bs[(lko + 5) * LDB + lrow] = b1.y;
    Bs[(lko + 6) * LDB + lrow] = b1.z;
    Bs[(lko + 7) * LDB + lrow] = b1.w;
    __syncthreads();
    if (kt + 16 < k1) {               // prefetch next tile
      a0 = *(const float4*)(Ap + kt + 16);
      a1 = *(const float4*)(Ap + kt + 20);
      b0 = *(const float4*)(Bp + kt + 16);
      b1 = *(const float4*)(Bp + kt + 20);
    }
    #pragma unroll
    for (int k = 0; k < 16; ++k) {
      float4 al = *(const float4*)(&As[k * LDB + (ty << 2)]);
      float4 ah = *(const float4*)(&As[k * LDB + 64 + (ty << 2)]);
      float4 bl = *(const float4*)(&Bs[k * LDB + (tx << 2)]);
      float4 bh = *(const float4*)(&Bs[k * LDB + 64 + (tx << 2)]);
      float af[8] = {al.x, al.y, al.z, al.w, ah.x, ah.y, ah.z, ah.w};
      float bf[8] = {bl.x, bl.y, bl.z, bl.w, bh.x, bh.y, bh.z, bh.w};
      #pragma unroll
      for (int i2 = 0; i2 < 8; ++i2)
        #pragma unroll
        for (int j2 = 0; j2 < 8; ++j2)
          acc[i2][j2] = fmaf(af[i2], bf[j2], acc[i2][j2]);
    }
  }
  #pragma unroll
  for (int i2 = 0; i2 < 8; ++i2) {
    int row = bm * 128 + ((i2 < 4) ? (ty << 2) + i2 : 64 + (ty << 2) + i2 - 4);
    float* Cp = C + (size_t)row * N + bn * 128;
    *(float4*)(Cp + (tx << 2))      = make_float4(acc[i2][0], acc[i2][1], acc[i2][2], acc[i2][3]);
    *(float4*)(Cp + 64 + (tx << 2)) = make_float4(acc[i2][4], acc[i2][5], acc[i2][6], acc[i2][7]);
  }
}

// d_out = fl32(p1 + p2)   (value path)
__global__ __launch_bounds__(256) void combine_kernel(const float* __restrict__ p1,
    const float* __restrict__ p2, float* __restrict__ out) {
  int i = blockIdx.x * 256 + threadIdx.x;
  out[i] = __fadd_rn(p1[i], p2[i]);
}

// qkv = fl32(p1+p2) (the contract's panel add), then RoPE + reshape.
__global__ __launch_bounds__(256) void rope_reshape_kernel(const float* __restrict__ p1,
    const float* __restrict__ p2, const float* __restrict__ cosT,
    const float* __restrict__ sinT, float* __restrict__ qb,
    float* __restrict__ kb, float* __restrict__ vb) {
  int idx = blockIdx.x * 256 + threadIdx.x;
  int s = idx >> 10;
  int n = idx & 1023;
  float val = __fadd_rn(p1[idx], p2[idx]);
  int d = n & 63;
  if (n < 768) {
    int dp = d & 31;
    float cs = cosT[(s << 5) + dp];
    float sn = sinT[(s << 5) + dp];
    int npart = (n - d) + ((d < 32) ? d + 32 : d - 32);
    int pidx = (s << 10) + npart;
    float partner = __fadd_rn(p1[pidx], p2[pidx]);
    float rot = (d < 32) ? -partner : partner;
    float out = __fadd_rn(__fmul_rn(val, cs), __fmul_rn(rot, sn));
    if (n < 512) {
      int h = n >> 6;
      qb[((size_t)(h * 4096 + s) << 6) + d] = out;
    } else {
      int kvh = (n - 512) >> 6;
      kb[((size_t)(kvh * 4096 + s) << 6) + d] = out;
    }
  } else {
    int kvh = (n - 768) >> 6;
    vb[((size_t)(kvh * 4096 + s) << 6) + d] = val;
  }
}

__global__ __launch_bounds__(256) void k12_np_kernel(const float* __restrict__ kb,
    float* __restrict__ k1t, float* __restrict__ k2t) {
  int id = blockIdx.x * 256 + threadIdx.x;    // 0..16383
  int which = id >> 13;
  int rem = id & 8191;
  int kvh = rem >> 11;
  int rem2 = rem & 2047;
  int i = rem2 >> 5;
  int d = rem2 & 31;
  const float* base = kb + ((size_t)(kvh * 4096) << 6);
  if (which == 0) {
    float acc = base[((size_t)(i * 64) << 6) + d];
    for (int c = 1; c < 64; ++c)
      acc = __fadd_rn(acc, base[((size_t)(i * 64 + c) << 6) + d]);
    k1t[(kvh * 64 + i) * 32 + d] = acc;
  } else {
    float acc = base[((size_t)i << 6) + d + 32];
    for (int r = 1; r < 64; ++r)
      acc = __fadd_rn(acc, base[((size_t)(r * 64 + i) << 6) + d + 32]);
    k2t[(kvh * 64 + i) * 32 + d] = acc;
  }
}

// Stage-1 scores as a tiled GEMM (fmaf chain over d ascending, per output).
__global__ __launch_bounds__(256) void stage1_scores_kernel(
    const float* __restrict__ qb, const float* __restrict__ k1t,
    const float* __restrict__ k2t, float* __restrict__ sc) {
  __shared__ float qs[64 * 68];     // [d][s]
  __shared__ float kd[32 * 132];    // [d][r2]
  const int t = threadIdx.x;
  const int h = blockIdx.y;
  const int s0 = blockIdx.x * 64;
  const int kvh = h >> 1;
  #pragma unroll
  for (int i = 0; i < 16; ++i) {
    int j = t + i * 256;
    int ss = j >> 6, d = j & 63;
    qs[d * 68 + ss] = qb[((size_t)(h * 4096 + s0 + ss) << 6) + d];
  }
  #pragma unroll
  for (int i = 0; i < 8; ++i) {
    int j = t + i * 256;
    int r = j >> 5, d = j & 31;
    kd[d * 132 + r]      = k1t[(kvh * 64 + r) * 32 + d];
    kd[d * 132 + 64 + r] = k2t[(kvh * 64 + r) * 32 + d];
  }
  __syncthreads();
  const int ty = t >> 4;
  const int tx = t & 15;
  const int qrow = (tx >= 8) ? 32 : 0;
  float acc[4][8] = {{0.f}};
  #pragma unroll
  for (int d = 0; d < 32; ++d) {
    float4 a4 = *(const float4*)&qs[(qrow + d) * 68 + (ty << 2)];
    float4 b0 = *(const float4*)&kd[d * 132 + (tx << 3)];
    float4 b1 = *(const float4*)&kd[d * 132 + (tx << 3) + 4];
    float af[4] = {a4.x, a4.y, a4.z, a4.w};
    float bf[8] = {b0.x, b0.y, b0.z, b0.w, b1.x, b1.y, b1.z, b1.w};
    #pragma unroll
    for (int i2 = 0; i2 < 4; ++i2)
      #pragma unroll
      for (int j2 = 0; j2 < 8; ++j2)
        acc[i2][j2] = fmaf(af[i2], bf[j2], acc[i2][j2]);
  }
  #pragma unroll
  for (int i2 = 0; i2 < 4; ++i2) {
    float* p = sc + (((size_t)(h * 4096 + s0 + (ty << 2) + i2)) << 7) + (tx << 3);
    *(float4*)(p)     = make_float4(acc[i2][0], acc[i2][1], acc[i2][2], acc[i2][3]);
    *(float4*)(p + 4) = make_float4(acc[i2][4], acc[i2][5], acc[i2][6], acc[i2][7]);
  }
}

// Values-only bitonic sort (descending).
__device__ __forceinline__ void bitonic64_val_desc(float& v, int lane) {
  #pragma unroll
  for (int k = 2; k <= 64; k <<= 1) {
    #pragma unroll
    for (int j = k >> 1; j >= 1; j >>= 1) {
      float ov = __shfl_xor(v, j, 64);
      bool up = ((lane & k) == 0) == ((lane & j) == 0);
      float mx = fmaxf(v, ov), mn = fminf(v, ov);
      v = up ? mx : mn;
    }
  }
}

// Selection kernel: one wave per (h,s); no LDS data at all.
__global__ __launch_bounds__(256) void attn_sel_kernel(const float* __restrict__ sc,
    const float* __restrict__ qb, const float* __restrict__ vb,
    const float* __restrict__ k1t, const float* __restrict__ k2t,
    float* __restrict__ ob) {
  const int lane = threadIdx.x & 63;
  const int w = blockIdx.x * 4 + (threadIdx.x >> 6);   // w = h*4096 + s
  const int h = w >> 12;
  const int s = w & 4095;
  const int kvh = h >> 1;
  const float* scp = sc + ((size_t)w << 7);
  const float s1 = scp[lane];
  const float s2 = scp[64 + lane];
  const float qv = qb[((size_t)w << 6) + lane];

  float v1 = s1;
  bitonic64_val_desc(v1, lane);
  unsigned long long pack1 = 0, used = 0;
  #pragma unroll
  for (int t = 0; t < 8; ++t) {
    float tv = rdlane_f(v1, t);
    unsigned long long m = __ballot(s1 == tv) & ~used;
    int ix = __ffsll((long long)m) - 1;
    used |= 1ull << ix;
    pack1 |= (unsigned long long)ix << (6 * t);
  }
  float v2 = s2;
  bitonic64_val_desc(v2, lane);
  unsigned long long pack2 = 0;
  used = 0;
  #pragma unroll
  for (int t = 0; t < 8; ++t) {
    float tv = rdlane_f(v2, t);
    unsigned long long m = __ballot(s2 == tv) & ~used;
    int ix = __ffsll((long long)m) - 1;
    used |= 1ull << ix;
    pack2 |= (unsigned long long)ix << (6 * t);
  }

  // stage-2: lane c = it1*8+it2; mul+add chain over d=0..63 (non-fma)
  int r1 = (int)((pack1 >> (6 * (lane >> 3))) & 63);
  int r2 = (int)((pack2 >> (6 * (lane & 7))) & 63);
  const float* k1p = k1t + (size_t)(kvh * 64 + r1) * 32;
  const float* k2p = k2t + (size_t)(kvh * 64 + r2) * 32;
  float c = 0.f;
  #pragma unroll
  for (int dq = 0; dq < 32; dq += 4) {
    float4 kk = *(const float4*)(k1p + dq);
    c = __fadd_rn(c, __fmul_rn(rdlane_f(qv, dq + 0), kk.x));
    c = __fadd_rn(c, __fmul_rn(rdlane_f(qv, dq + 1), kk.y));
    c = __fadd_rn(c, __fmul_rn(rdlane_f(qv, dq + 2), kk.z));
    c = __fadd_rn(c, __fmul_rn(rdlane_f(qv, dq + 3), kk.w));
  }
  #pragma unroll
  for (int dq = 0; dq < 32; dq += 4) {
    float4 kk = *(const float4*)(k2p + dq);
    c = __fadd_rn(c, __fmul_rn(rdlane_f(qv, 32 + dq + 0), kk.x));
    c = __fadd_rn(c, __fmul_rn(rdlane_f(qv, 32 + dq + 1), kk.y));
    c = __fadd_rn(c, __fmul_rn(rdlane_f(qv, 32 + dq + 2), kk.z));
    c = __fadd_rn(c, __fmul_rn(rdlane_f(qv, 32 + dq + 3), kk.w));
  }
  const float scand = c;
  float v3 = c;
  bitonic64_val_desc(v3, lane);
  float cvs[8]; int ccs[8];
  used = 0;
  #pragma unroll
  for (int t = 0; t < 8; ++t) {
    float tv = rdlane_f(v3, t);
    unsigned long long m = __ballot(scand == tv) & ~used;
    int ix = __ffsll((long long)m) - 1;
    used |= 1ull << ix;
    cvs[t] = tv;
    ccs[t] = ix;
  }
  float y[8];
  #pragma unroll
  for (int t = 0; t < 8; ++t) y[t] = cvs[t] * 0.125f;
  float mx = y[0];
  #pragma unroll
  for (int t = 1; t < 8; ++t) if (y[t] > mx) mx = y[t];
  float e[8];
  #pragma unroll
  for (int t = 0; t < 8; ++t) e[t] = __expf(__fsub_rn(y[t], mx));
  float wsum = __fadd_rn(__fadd_rn(__fadd_rn(e[0], e[1]), __fadd_rn(e[2], e[3])),
                         __fadd_rn(__fadd_rn(e[4], e[5]), __fadd_rn(e[6], e[7])));
  const float* vbh = vb + ((size_t)kvh << 18);
  float o = 0.f;
  #pragma unroll
  for (int t = 0; t < 8; ++t) {
    float att = __fdiv_rn(e[t], wsum);
    int row = (int)((pack1 >> (6 * (ccs[t] >> 3))) & 63);
    int col = (int)((pack2 >> (6 * (ccs[t] & 7))) & 63);
    o = __fadd_rn(o, __fmul_rn(att, vbh[((size_t)(row * 64 + col) << 6) + lane]));
  }
  ob[(size_t)s * 512 + (h << 6) + lane] = o;
}

extern "C" void kernel_launch(void* const* d_in, const int* in_sizes, int n_in,
                              void* d_out, int out_size, void* d_ws, size_t ws_size,
                              hipStream_t stream) {
  const float* x  = (const float*)d_in[0];
  const float* Wq = (const float*)d_in[1];
  const float* Wk = (const float*)d_in[2];
  const float* Wv = (const float*)d_in[3];
  const float* Wo = (const float*)d_in[4];
  float* ws = (float*)d_ws;
  float* p1   = ws + OFF_P1;
  float* p2   = ws + OFF_P2;
  float* qb   = ws + OFF_Q;
  float* kb   = ws + OFF_K;
  float* vb   = ws + OFF_V;
  float* cosT = ws + OFF_COS;
  float* sinT = ws + OFF_SIN;
  float* k1t  = ws + OFF_K1;
  float* k2t  = ws + OFF_K2;
  float* ob   = ws + OFF_O;
  float* wcat = ws + OFF_W;
  float* scb  = ws + OFF_P1;          // scores reuse panel1 buffer
  float* op1  = ws + OFF_P2;          // out partials reuse panel2 buffer
  float* op2  = ws + OFF_P2 + 2097152;

  hipMemcpyAsync(wcat,             Wq, (size_t)512 * 512 * sizeof(float), hipMemcpyDeviceToDevice, stream);
  hipMemcpyAsync(wcat + 512 * 512, Wk, (size_t)256 * 512 * sizeof(float), hipMemcpyDeviceToDevice, stream);
  hipMemcpyAsync(wcat + 768 * 512, Wv, (size_t)256 * 512 * sizeof(float), hipMemcpyDeviceToDevice, stream);

  freq_table_kernel<<<512, 256, 0, stream>>>(cosT, sinT);
  // QKV: selection-critical KC=384 panel split via grid-z
  gemm128_panel<<<dim3(8, 32, 2), 256, 0, stream>>>(x, wcat, p1, p2, 1024, 384);
  rope_reshape_kernel<<<16384, 256, 0, stream>>>(p1, p2, cosT, sinT, qb, kb, vb);
  k12_np_kernel<<<64, 256, 0, stream>>>(kb, k1t, k2t);
  stage1_scores_kernel<<<dim3(64, 8), 256, 0, stream>>>(qb, k1t, k2t, scb);
  attn_sel_kernel<<<8192, 256, 0, stream>>>(scb, qb, vb, k1t, k2t, ob);
  // Output projection: value-path, split-k at 256 via grid-z + combine
  gemm128_panel<<<dim3(4, 32, 2), 256, 0, stream>>>(ob, Wo, op1, op2, 512, 256);
  combine_kernel<<<8192, 256, 0, stream>>>(op1, op2, (float*)d_out);
}